// Round 1
// baseline (251.088 us; speedup 1.0000x reference)
//
#include <hip/hip_runtime.h>
#include <hip/hip_bf16.h>
#include <stdint.h>

// MHA: x[4,2048,1024] fp32 -> out fp32. All GEMMs in bf16 MFMA 16x16x32, fp32 accum.
// B=4, C=2048, D=1024, H=16, Dh=64.

typedef __attribute__((ext_vector_type(8))) short short8;   // 8 bf16 (4 VGPRs) MFMA A/B frag
typedef __attribute__((ext_vector_type(4))) short short4v;
typedef __attribute__((ext_vector_type(4))) float f32x4;    // MFMA C/D frag

#define AS1 __attribute__((address_space(1)))
#define AS3 __attribute__((address_space(3)))

static __device__ __forceinline__ short f2bf(float f) {
  union { float f; uint32_t u; } v; v.f = f;
  uint32_t r = v.u + 0x7fffu + ((v.u >> 16) & 1u);   // RNE
  return (short)(r >> 16);
}

static __device__ __forceinline__ void gload_lds16(const void* g, void* l) {
  __builtin_amdgcn_global_load_lds((const AS1 void*)g, (AS3 void*)l, 16, 0, 0);
}

// ---------------- x fp32 -> bf16 ----------------
__global__ __launch_bounds__(256) void k_cvt_x(const float* __restrict__ x,
                                               short* __restrict__ xb) {
  long i = ((long)blockIdx.x * 256 + threadIdx.x) * 4;
  const float4 v = *(const float4*)(x + i);
  short4v o;
  o[0] = f2bf(v.x); o[1] = f2bf(v.y); o[2] = f2bf(v.z); o[3] = f2bf(v.w);
  *(short4v*)(xb + i) = o;
}

// ---------------- W [K][N] fp32 -> Wt [N][K] bf16 ----------------
__global__ __launch_bounds__(256) void k_transpose_bf(const float* __restrict__ W,
                                                      short* __restrict__ Wt,
                                                      int K, int N) {
  __shared__ float t[64][65];
  const int nb = blockIdx.x * 64, kb = blockIdx.y * 64;
  const int tid = threadIdx.x;
#pragma unroll
  for (int i = 0; i < 16; ++i) {
    int idx = i * 256 + tid; int r = idx >> 6, c = idx & 63;
    t[r][c] = W[(long)(kb + r) * N + nb + c];
  }
  __syncthreads();
#pragma unroll
  for (int i = 0; i < 16; ++i) {
    int idx = i * 256 + tid; int r = idx >> 6, c = idx & 63;
    Wt[(long)(nb + r) * K + kb + c] = f2bf(t[c][r]);
  }
}

// ---------------- bf16 GEMM, 128x128 tile, BK=32 (m97 structure) ----------------
// A [M][K] bf16 row-major, Bt [N][K] bf16 row-major (= B^T). C = A*B + bias.
// EPI 0: scatter to Q (x0.125) / K / V^T bf16 workspaces.  EPI 1: fp32 C + bias.
template <int EPI>
__global__ __launch_bounds__(256)
void k_gemm(const short* __restrict__ A, const short* __restrict__ Bt,
            const float* __restrict__ bias, float* __restrict__ Cf,
            short* __restrict__ q_ws, short* __restrict__ k_ws, short* __restrict__ vt_ws,
            int M, int N, int K) {
  __shared__ __align__(16) short a_sh[128 * 32];
  __shared__ __align__(16) short b_sh[128 * 32];
  const int tid = threadIdx.x;
  const int lane = tid & 63, wid = tid >> 6;
  const int l15 = lane & 15, lg = lane >> 4;
  const int wr = wid >> 1, wc = wid & 1;                 // 2x2 waves, 64x64 each
  const int m0 = blockIdx.y * 128, n0 = blockIdx.x * 128;

  f32x4 acc[4][4] = {};

  const int r0 = tid >> 2, g0 = tid & 3;                 // staging: row r0(+64), 8-elem granule g0
  const short* ga0 = A + (long)(m0 + r0) * K + g0 * 8;
  const short* gb0 = Bt + (long)(n0 + r0) * K + g0 * 8;

  for (int ks = 0; ks < K; ks += 32) {
    __syncthreads();
#pragma unroll
    for (int i = 0; i < 2; ++i) {
      gload_lds16(ga0 + (long)i * 64 * K + ks, a_sh + (i * 256 + tid) * 8);
      gload_lds16(gb0 + (long)i * 64 * K + ks, b_sh + (i * 256 + tid) * 8);
    }
    asm volatile("s_waitcnt vmcnt(0)" ::: "memory");
    __syncthreads();

    short8 af[4], bfr[4];
#pragma unroll
    for (int m = 0; m < 4; ++m)
      af[m] = *(const short8*)(a_sh + (wr * 64 + m * 16 + l15) * 32 + lg * 8);
#pragma unroll
    for (int n = 0; n < 4; ++n)
      bfr[n] = *(const short8*)(b_sh + (wc * 64 + n * 16 + l15) * 32 + lg * 8);
#pragma unroll
    for (int m = 0; m < 4; ++m)
#pragma unroll
      for (int n = 0; n < 4; ++n)
        acc[m][n] = __builtin_amdgcn_mfma_f32_16x16x32_bf16(af[m], bfr[n], acc[m][n], 0, 0, 0);
  }

  // epilogue: C/D layout row=(lane>>4)*4+reg, col=lane&15 (m89-verified)
#pragma unroll
  for (int mm = 0; mm < 4; ++mm) {
#pragma unroll
    for (int nn = 0; nn < 4; ++nn) {
#pragma unroll
      for (int r = 0; r < 4; ++r) {
        int m = m0 + wr * 64 + mm * 16 + lg * 4 + r;
        int n = n0 + wc * 64 + nn * 16 + l15;
        float v = acc[mm][nn][r] + bias[n];
        if (EPI == 0) {
          int b = m >> 11, c = m & 2047;
          int which = n >> 10, h = (n >> 6) & 15, d = n & 63;
          int bh = b * 16 + h;
          if (which == 0)      q_ws[((long)bh * 2048 + c) * 64 + d] = f2bf(v * 0.125f);
          else if (which == 1) k_ws[((long)bh * 2048 + c) * 64 + d] = f2bf(v);
          else                 vt_ws[((long)bh * 64 + d) * 2048 + c] = f2bf(v);
        } else {
          Cf[(long)m * N + n] = v;
        }
      }
    }
  }
}

// ---------------- flash attention ----------------
// grid (B*H, C/64); block 256 = 4 waves x 16 q-rows. KV tiles of 64 in LDS.
// LDS tiles are 64x64 bf16 (row = 128B): XOR-swizzle 16B granule with (row&7);
// gload_lds writes linearly, so the swizzle is applied to the GLOBAL source (m173).
__global__ __launch_bounds__(256)
void k_attn(const short* __restrict__ q_ws, const short* __restrict__ k_ws,
            const short* __restrict__ vt_ws, short* __restrict__ attn_out) {
  __shared__ __align__(16) short k_sh[64 * 64];
  __shared__ __align__(16) short v_sh[64 * 64];   // V^T tile: row=d, col=kv
  __shared__ __align__(16) short p_sh[4 * 16 * 64];  // per-wave P tile

  const int tid = threadIdx.x;
  const int lane = tid & 63, wid = tid >> 6;
  const int l15 = lane & 15, lg = lane >> 4;
  const int bh = blockIdx.x, qt = blockIdx.y;
  const int b = bh >> 4, h = bh & 15;
  const int qbase = qt * 64 + wid * 16;

  // Q fragments (16 rows x 64 d), Q pre-scaled by 1/8
  const short* qrow = q_ws + ((long)bh * 2048 + qbase + l15) * 64;
  const short8 qf0 = *(const short8*)(qrow + lg * 8);
  const short8 qf1 = *(const short8*)(qrow + 32 + lg * 8);

  f32x4 accO[4] = {};
  float mrow[4] = {-1e30f, -1e30f, -1e30f, -1e30f};
  float lrow[4] = {0.f, 0.f, 0.f, 0.f};

  const int srow = tid >> 3, sg = tid & 7;   // staging: granule (row, sg)

  const int nkv = qt + 1;
  for (int t = 0; t < nkv; ++t) {
    const int kv = t * 64;
    __syncthreads();
#pragma unroll
    for (int i = 0; i < 2; ++i) {
      int row = i * 32 + srow;
      int gl = sg ^ (row & 7);               // pre-swizzled source granule
      gload_lds16(k_ws + ((long)bh * 2048 + kv + row) * 64 + gl * 8,
                  k_sh + (i * 256 + tid) * 8);
      gload_lds16(vt_ws + ((long)bh * 64 + row) * 2048 + kv + gl * 8,
                  v_sh + (i * 256 + tid) * 8);
    }
    asm volatile("s_waitcnt vmcnt(0)" ::: "memory");
    __syncthreads();

    // S = Q K^T  (4 tiles of 16 kv cols; K-dim 64 = 2 MFMAs)
    f32x4 s[4];
#pragma unroll
    for (int j = 0; j < 4; ++j) {
      int row = j * 16 + l15;
      short8 kf0 = *(const short8*)(k_sh + row * 64 + ((lg ^ (row & 7)) << 3));
      short8 kf1 = *(const short8*)(k_sh + row * 64 + (((4 + lg) ^ (row & 7)) << 3));
      f32x4 z = {};
      z = __builtin_amdgcn_mfma_f32_16x16x32_bf16(qf0, kf0, z, 0, 0, 0);
      z = __builtin_amdgcn_mfma_f32_16x16x32_bf16(qf1, kf1, z, 0, 0, 0);
      s[j] = z;
    }

    // causal mask (only tiles overlapping the diagonal)
    if (kv + 64 > qbase) {
#pragma unroll
      for (int j = 0; j < 4; ++j) {
        int col = kv + j * 16 + l15;
#pragma unroll
        for (int r = 0; r < 4; ++r) {
          int row = qbase + lg * 4 + r;
          if (col > row) s[j][r] = -1e30f;
        }
      }
    }

    // online softmax (rows live in 16-lane groups: row=(lg)*4+r, col=l15)
#pragma unroll
    for (int r = 0; r < 4; ++r) {
      float mx = fmaxf(fmaxf(s[0][r], s[1][r]), fmaxf(s[2][r], s[3][r]));
      mx = fmaxf(mx, __shfl_xor(mx, 1));
      mx = fmaxf(mx, __shfl_xor(mx, 2));
      mx = fmaxf(mx, __shfl_xor(mx, 4));
      mx = fmaxf(mx, __shfl_xor(mx, 8));
      float mnew = fmaxf(mrow[r], mx);
      float sc = __expf(mrow[r] - mnew);
      mrow[r] = mnew;
      lrow[r] *= sc;
      accO[0][r] *= sc; accO[1][r] *= sc; accO[2][r] *= sc; accO[3][r] *= sc;
      const int prow = lg * 4 + r;
      const int pbase = wid * 1024 + prow * 64;
      float ps = 0.f;
#pragma unroll
      for (int j = 0; j < 4; ++j) {
        float p = __expf(s[j][r] - mnew);
        ps += p;
        int col = j * 16 + l15;
        p_sh[pbase + ((((col >> 3) ^ (prow & 7)) << 3) | (col & 7))] = f2bf(p);
      }
      lrow[r] += ps;   // per-lane partial (4 of 64 cols); reduced at end
    }

    // O += P V   (wave-private p_sh: in-order DS pipe, no barrier needed)
#pragma unroll
    for (int dt = 0; dt < 4; ++dt) {
#pragma unroll
      for (int p = 0; p < 2; ++p) {
        short8 pf = *(const short8*)(p_sh + wid * 1024 + l15 * 64 +
                                     (((p * 4 + lg) ^ (l15 & 7)) << 3));
        int vrow = dt * 16 + l15;
        short8 vf = *(const short8*)(v_sh + vrow * 64 +
                                     (((p * 4 + lg) ^ (vrow & 7)) << 3));
        accO[dt] = __builtin_amdgcn_mfma_f32_16x16x32_bf16(pf, vf, accO[dt], 0, 0, 0);
      }
    }
  }

  // epilogue: O /= l, write [B,C,H*Dh] bf16
#pragma unroll
  for (int r = 0; r < 4; ++r) {
    float lr = lrow[r];
    lr += __shfl_xor(lr, 1);
    lr += __shfl_xor(lr, 2);
    lr += __shfl_xor(lr, 4);
    lr += __shfl_xor(lr, 8);
    float inv = 1.0f / lr;
    int qg = qbase + lg * 4 + r;
    long base = ((long)b * 2048 + qg) * 1024 + h * 64;
#pragma unroll
    for (int dt = 0; dt < 4; ++dt)
      attn_out[base + dt * 16 + l15] = f2bf(accO[dt][r] * inv);
  }
}

// ---------------- launch ----------------
extern "C" void kernel_launch(void* const* d_in, const int* in_sizes, int n_in,
                              void* d_out, int out_size, void* d_ws, size_t ws_size,
                              hipStream_t stream) {
  const float* x     = (const float*)d_in[0];
  const float* W_qkv = (const float*)d_in[1];
  const float* b_qkv = (const float*)d_in[2];
  const float* W_o   = (const float*)d_in[3];
  const float* b_o   = (const float*)d_in[4];
  float* out = (float*)d_out;

  char* ws = (char*)d_ws;
  short* x_bf   = (short*)(ws);               // 16 MB; reused as attn_out after GEMM1
  short* wqkv_t = (short*)(ws + 16777216);    // 6 MB  [3072][1024]
  short* wo_t   = (short*)(ws + 23068672);    // 2 MB  [1024][1024]
  short* q_ws   = (short*)(ws + 25165824);    // 16 MB [B*H][C][64], pre-scaled
  short* k_ws   = (short*)(ws + 41943040);    // 16 MB [B*H][C][64]
  short* vt_ws  = (short*)(ws + 58720256);    // 16 MB [B*H][64][C]  (V^T)

  k_cvt_x<<<dim3(8192), dim3(256), 0, stream>>>(x, x_bf);
  k_transpose_bf<<<dim3(48, 16), dim3(256), 0, stream>>>(W_qkv, wqkv_t, 1024, 3072);
  k_transpose_bf<<<dim3(16, 16), dim3(256), 0, stream>>>(W_o, wo_t, 1024, 1024);
  k_gemm<0><<<dim3(24, 64), dim3(256), 0, stream>>>(x_bf, wqkv_t, b_qkv, nullptr,
                                                    q_ws, k_ws, vt_ws, 8192, 3072, 1024);
  k_attn<<<dim3(64, 32), dim3(256), 0, stream>>>(q_ws, k_ws, vt_ws, x_bf);
  k_gemm<1><<<dim3(8, 64), dim3(256), 0, stream>>>(x_bf, wo_t, b_o, out,
                                                   nullptr, nullptr, nullptr, 8192, 1024, 1024);
}

// Round 2
// 210.061 us; speedup vs baseline: 1.1953x; 1.1953x over previous
//
#include <hip/hip_runtime.h>
#include <hip/hip_bf16.h>
#include <stdint.h>

// MHA: x[4,2048,1024] fp32 -> out fp32. All GEMMs in bf16 MFMA 16x16x32, fp32 accum.
// B=4, C=2048, D=1024, H=16, Dh=64.

typedef __attribute__((ext_vector_type(8))) short short8;   // 8 bf16 (4 VGPRs) MFMA A/B frag
typedef __attribute__((ext_vector_type(4))) short short4v;
typedef __attribute__((ext_vector_type(4))) float f32x4;    // MFMA C/D frag

#define AS1 __attribute__((address_space(1)))
#define AS3 __attribute__((address_space(3)))

static __device__ __forceinline__ short f2bf(float f) {
  union { float f; uint32_t u; } v; v.f = f;
  uint32_t r = v.u + 0x7fffu + ((v.u >> 16) & 1u);   // RNE
  return (short)(r >> 16);
}

static __device__ __forceinline__ short f2bfh(float f) {
  __hip_bfloat16 h = __float2bfloat16(f);             // HW cvt, pairs fuse to v_cvt_pk_bf16_f32
  return *reinterpret_cast<short*>(&h);
}

static __device__ __forceinline__ void gload_lds16(const void* g, void* l) {
  __builtin_amdgcn_global_load_lds((const AS1 void*)g, (AS3 void*)l, 16, 0, 0);
}

// ---------------- x fp32 -> bf16 ----------------
__global__ __launch_bounds__(256) void k_cvt_x(const float* __restrict__ x,
                                               short* __restrict__ xb) {
  long i = ((long)blockIdx.x * 256 + threadIdx.x) * 4;
  const float4 v = *(const float4*)(x + i);
  short4v o;
  o[0] = f2bf(v.x); o[1] = f2bf(v.y); o[2] = f2bf(v.z); o[3] = f2bf(v.w);
  *(short4v*)(xb + i) = o;
}

// ---------------- W [K][N] fp32 -> Wt [N][K] bf16 ----------------
__global__ __launch_bounds__(256) void k_transpose_bf(const float* __restrict__ W,
                                                      short* __restrict__ Wt,
                                                      int K, int N) {
  __shared__ float t[64][65];
  const int nb = blockIdx.x * 64, kb = blockIdx.y * 64;
  const int tid = threadIdx.x;
#pragma unroll
  for (int i = 0; i < 16; ++i) {
    int idx = i * 256 + tid; int r = idx >> 6, c = idx & 63;
    t[r][c] = W[(long)(kb + r) * N + nb + c];
  }
  __syncthreads();
#pragma unroll
  for (int i = 0; i < 16; ++i) {
    int idx = i * 256 + tid; int r = idx >> 6, c = idx & 63;
    Wt[(long)(nb + r) * K + kb + c] = f2bf(t[c][r]);
  }
}

// ---------------- bf16 GEMM, 128x128 tile, BK=32 (m97 structure) ----------------
// A [M][K] bf16 row-major, Bt [N][K] bf16 row-major (= B^T). C = A*B + bias.
// EPI 0: scatter to Q (x0.125) / K / V^T bf16 workspaces.  EPI 1: fp32 C + bias.
template <int EPI>
__global__ __launch_bounds__(256)
void k_gemm(const short* __restrict__ A, const short* __restrict__ Bt,
            const float* __restrict__ bias, float* __restrict__ Cf,
            short* __restrict__ q_ws, short* __restrict__ k_ws, short* __restrict__ vt_ws,
            int M, int N, int K) {
  __shared__ __align__(16) short a_sh[128 * 32];
  __shared__ __align__(16) short b_sh[128 * 32];
  const int tid = threadIdx.x;
  const int lane = tid & 63, wid = tid >> 6;
  const int l15 = lane & 15, lg = lane >> 4;
  const int wr = wid >> 1, wc = wid & 1;                 // 2x2 waves, 64x64 each
  const int m0 = blockIdx.y * 128, n0 = blockIdx.x * 128;

  f32x4 acc[4][4] = {};

  const int r0 = tid >> 2, g0 = tid & 3;                 // staging: row r0(+64), 8-elem granule g0
  const short* ga0 = A + (long)(m0 + r0) * K + g0 * 8;
  const short* gb0 = Bt + (long)(n0 + r0) * K + g0 * 8;

  for (int ks = 0; ks < K; ks += 32) {
    __syncthreads();
#pragma unroll
    for (int i = 0; i < 2; ++i) {
      gload_lds16(ga0 + (long)i * 64 * K + ks, a_sh + (i * 256 + tid) * 8);
      gload_lds16(gb0 + (long)i * 64 * K + ks, b_sh + (i * 256 + tid) * 8);
    }
    asm volatile("s_waitcnt vmcnt(0)" ::: "memory");
    __syncthreads();

    short8 af[4], bfr[4];
#pragma unroll
    for (int m = 0; m < 4; ++m)
      af[m] = *(const short8*)(a_sh + (wr * 64 + m * 16 + l15) * 32 + lg * 8);
#pragma unroll
    for (int n = 0; n < 4; ++n)
      bfr[n] = *(const short8*)(b_sh + (wc * 64 + n * 16 + l15) * 32 + lg * 8);
#pragma unroll
    for (int m = 0; m < 4; ++m)
#pragma unroll
      for (int n = 0; n < 4; ++n)
        acc[m][n] = __builtin_amdgcn_mfma_f32_16x16x32_bf16(af[m], bfr[n], acc[m][n], 0, 0, 0);
  }

  // epilogue: C/D layout row=(lane>>4)*4+reg, col=lane&15 (m89-verified)
#pragma unroll
  for (int mm = 0; mm < 4; ++mm) {
#pragma unroll
    for (int nn = 0; nn < 4; ++nn) {
#pragma unroll
      for (int r = 0; r < 4; ++r) {
        int m = m0 + wr * 64 + mm * 16 + lg * 4 + r;
        int n = n0 + wc * 64 + nn * 16 + l15;
        float v = acc[mm][nn][r] + bias[n];
        if (EPI == 0) {
          int b = m >> 11, c = m & 2047;
          int which = n >> 10, h = (n >> 6) & 15, d = n & 63;
          int bh = b * 16 + h;
          if (which == 0)      q_ws[((long)bh * 2048 + c) * 64 + d] = f2bf(v * 0.125f);
          else if (which == 1) k_ws[((long)bh * 2048 + c) * 64 + d] = f2bf(v);
          else                 vt_ws[((long)bh * 64 + d) * 2048 + c] = f2bf(v);
        } else {
          Cf[(long)m * N + n] = v;
        }
      }
    }
  }
}

// ---------------- flash attention, swapped-operand (m214 structure) ----------------
// grid (B*H, C/64); block 256 = 4 waves x 16 q-rows each. KV tiles of 64, double-buffered.
// QK^T swapped: S^T = mfma(K_frag, Q_frag) -> lane holds 16 S values for ONE q (= lane&15).
// Softmax fully in-register (15 fmax + 2 shfl). PV swapped: O^T = mfma(V^T_frag, P_frag)
// with kv-permutation sigma(lg,i)=16*(i>>2)+4lg+(i&3) so the P B-frag is the lane's own
// 16 exp values (zero cross-lane, zero LDS for P). V A-frag = 2x ds_read_b64 per MFMA.
// LDS tiles row=128B -> XOR-swizzle 16B granules with (row&7); row&7 == l15&7 for all frag
// reads, so swizzled offsets are lane constants. gload_lds writes linearly; swizzle is
// applied on the GLOBAL source (m173).
__global__ __launch_bounds__(256)
void k_attn(const short* __restrict__ q_ws, const short* __restrict__ k_ws,
            const short* __restrict__ vt_ws, short* __restrict__ attn_out) {
  __shared__ __align__(16) short k_sh[2][64 * 64];
  __shared__ __align__(16) short v_sh[2][64 * 64];   // V^T tile: row=d, col=kv

  const int tid = threadIdx.x;
  const int lane = tid & 63, wid = tid >> 6;
  const int l15 = lane & 15, lg = lane >> 4;
  const int bh = blockIdx.x;
  const int qt = (int)gridDim.y - 1 - (int)blockIdx.y;   // heavy blocks first
  const int b = bh >> 4, h = bh & 15;
  const int qw = qt * 64 + wid * 16;                     // wave's q base
  const int q_glob = qw + l15;                           // this lane's q row

  // Q B-frags (lane: q=l15 col, d=lg*8.. contiguous), Q pre-scaled by 1/8
  const short* qrow = q_ws + ((long)bh * 2048 + q_glob) * 64;
  const short8 qf0 = *(const short8*)(qrow + lg * 8);
  const short8 qf1 = *(const short8*)(qrow + 32 + lg * 8);

  // lane-constant swizzled LDS byte offsets (swizzle key s7 = row&7 = l15&7)
  const int s7 = l15 & 7;
  const int koff0 = ((lg ^ s7) << 4);          // K granule lg   (d 8lg..8lg+7)
  const int koff1 = (((4 + lg) ^ s7) << 4);    // K granule 4+lg (d 32+8lg..)
  const int vsub = (lg & 1) * 8, vg = lg >> 1;
  int voff[4];
#pragma unroll
  for (int m2 = 0; m2 < 4; ++m2)               // V bytes {8lg,32+8lg,64+8lg,96+8lg}
    voff[m2] = (((2 * m2 + vg) ^ s7) << 4) | vsub;

  f32x4 accO[4] = {};                          // O^T: lane holds d=dt*16+lg*4+r, q=l15
  float mrow = -1e30f, lrow = 0.f;

  const int srow = tid >> 3, sg = tid & 7;     // staging granule (row, col)
  const int nkv = qt + 1;

#define STAGE(buf, kv)                                                              \
  {                                                                                 \
    _Pragma("unroll")                                                               \
    for (int i = 0; i < 2; ++i) {                                                   \
      int row = i * 32 + srow;                                                      \
      int gl = sg ^ (row & 7);                                                      \
      gload_lds16(k_ws + ((long)bh * 2048 + (kv) + row) * 64 + gl * 8,              \
                  &k_sh[buf][(i * 256 + tid) * 8]);                                 \
      gload_lds16(vt_ws + ((long)bh * 64 + row) * 2048 + (kv) + gl * 8,             \
                  &v_sh[buf][(i * 256 + tid) * 8]);                                 \
    }                                                                               \
  }

  STAGE(0, 0);
  asm volatile("s_waitcnt vmcnt(0)" ::: "memory");
  __syncthreads();

  int cur = 0;
  for (int t = 0; t < nkv; ++t) {
    const int kv0 = t * 64;
    if (t + 1 < nkv) STAGE(cur ^ 1, kv0 + 64);

    const char* ksh = (const char*)k_sh[cur];
    const char* vsh = (const char*)v_sh[cur];

    // S^T tiles: st[j][r] = S[q=l15][kv = kv0 + 16j + 4lg + r]
    f32x4 st[4];
#pragma unroll
    for (int j = 0; j < 4; ++j) {
      const char* kr = ksh + (j * 16 + l15) * 128;
      short8 kf0 = *(const short8*)(kr + koff0);
      short8 kf1 = *(const short8*)(kr + koff1);
      f32x4 z = {};
      z = __builtin_amdgcn_mfma_f32_16x16x32_bf16(kf0, qf0, z, 0, 0, 0);
      z = __builtin_amdgcn_mfma_f32_16x16x32_bf16(kf1, qf1, z, 0, 0, 0);
      st[j] = z;
    }

    // causal mask (diagonal tile only)
    if (kv0 + 64 > qw) {
#pragma unroll
      for (int j = 0; j < 4; ++j) {
        int kvr = kv0 + j * 16 + lg * 4;
#pragma unroll
        for (int r = 0; r < 4; ++r)
          if (kvr + r > q_glob) st[j][r] = -1e30f;
      }
    }

    // online softmax: all state per-lane (q = l15)
    float a0 = fmaxf(fmaxf(st[0][0], st[0][1]), fmaxf(st[0][2], st[0][3]));
    float a1 = fmaxf(fmaxf(st[1][0], st[1][1]), fmaxf(st[1][2], st[1][3]));
    float a2 = fmaxf(fmaxf(st[2][0], st[2][1]), fmaxf(st[2][2], st[2][3]));
    float a3 = fmaxf(fmaxf(st[3][0], st[3][1]), fmaxf(st[3][2], st[3][3]));
    float mx = fmaxf(fmaxf(a0, a1), fmaxf(a2, a3));
    mx = fmaxf(mx, __shfl_xor(mx, 16));
    mx = fmaxf(mx, __shfl_xor(mx, 32));
    const float mnew = fmaxf(mrow, mx);
    const float sc = __expf(mrow - mnew);
    mrow = mnew;
    lrow *= sc;
#pragma unroll
    for (int dt = 0; dt < 4; ++dt) {
      accO[dt][0] *= sc; accO[dt][1] *= sc; accO[dt][2] *= sc; accO[dt][3] *= sc;
    }
    float ps = 0.f;
#pragma unroll
    for (int j = 0; j < 4; ++j)
#pragma unroll
      for (int r = 0; r < 4; ++r) {
        float e = __expf(st[j][r] - mnew);
        st[j][r] = e;
        ps += e;
      }
    lrow += ps;   // partial over this lane's 16 kv slots; lg-reduced at end

    // pack P to bf16 B-frags (lane's own values; slot i of frag1 = sigma(lg,i))
    short8 pb0, pb1;
#pragma unroll
    for (int r = 0; r < 4; ++r) {
      pb0[r]     = f2bfh(st[0][r]);
      pb0[4 + r] = f2bfh(st[1][r]);
      pb1[r]     = f2bfh(st[2][r]);
      pb1[4 + r] = f2bfh(st[3][r]);
    }

    // O^T += V^T . P^T  (A-frag slot (lg,i) = V^T[d][sigma(lg,i)], 2x b64 per frag)
#pragma unroll
    for (int dt = 0; dt < 4; ++dt) {
      const char* vr = vsh + (dt * 16 + l15) * 128;
      union { short8 s8; short4v s4[2]; } vf1, vf2;
      vf1.s4[0] = *(const short4v*)(vr + voff[0]);
      vf1.s4[1] = *(const short4v*)(vr + voff[1]);
      accO[dt] = __builtin_amdgcn_mfma_f32_16x16x32_bf16(vf1.s8, pb0, accO[dt], 0, 0, 0);
      vf2.s4[0] = *(const short4v*)(vr + voff[2]);
      vf2.s4[1] = *(const short4v*)(vr + voff[3]);
      accO[dt] = __builtin_amdgcn_mfma_f32_16x16x32_bf16(vf2.s8, pb1, accO[dt], 0, 0, 0);
    }

    asm volatile("s_waitcnt vmcnt(0)" ::: "memory");
    __syncthreads();
    cur ^= 1;
  }
#undef STAGE

  // epilogue: O = O^T / l ; write [B,C,H*Dh] bf16, 8B stores
  float lt = lrow;
  lt += __shfl_xor(lt, 16);
  lt += __shfl_xor(lt, 32);
  const float inv = 1.0f / lt;
  short* obase = attn_out + ((long)b * 2048 + q_glob) * 1024 + h * 64;
#pragma unroll
  for (int dt = 0; dt < 4; ++dt) {
    short4v o;
#pragma unroll
    for (int r = 0; r < 4; ++r) o[r] = f2bfh(accO[dt][r] * inv);
    *(short4v*)(obase + dt * 16 + lg * 4) = o;
  }
}

// ---------------- launch ----------------
extern "C" void kernel_launch(void* const* d_in, const int* in_sizes, int n_in,
                              void* d_out, int out_size, void* d_ws, size_t ws_size,
                              hipStream_t stream) {
  const float* x     = (const float*)d_in[0];
  const float* W_qkv = (const float*)d_in[1];
  const float* b_qkv = (const float*)d_in[2];
  const float* W_o   = (const float*)d_in[3];
  const float* b_o   = (const float*)d_in[4];
  float* out = (float*)d_out;

  char* ws = (char*)d_ws;
  short* x_bf   = (short*)(ws);               // 16 MB; reused as attn_out after GEMM0
  short* wqkv_t = (short*)(ws + 16777216);    // 6 MB  [3072][1024]
  short* wo_t   = (short*)(ws + 23068672);    // 2 MB  [1024][1024]
  short* q_ws   = (short*)(ws + 25165824);    // 16 MB [B*H][C][64], pre-scaled
  short* k_ws   = (short*)(ws + 41943040);    // 16 MB [B*H][C][64]
  short* vt_ws  = (short*)(ws + 58720256);    // 16 MB [B*H][64][C]  (V^T)

  k_cvt_x<<<dim3(8192), dim3(256), 0, stream>>>(x, x_bf);
  k_transpose_bf<<<dim3(48, 16), dim3(256), 0, stream>>>(W_qkv, wqkv_t, 1024, 3072);
  k_transpose_bf<<<dim3(16, 16), dim3(256), 0, stream>>>(W_o, wo_t, 1024, 1024);
  k_gemm<0><<<dim3(24, 64), dim3(256), 0, stream>>>(x_bf, wqkv_t, b_qkv, nullptr,
                                                    q_ws, k_ws, vt_ws, 8192, 3072, 1024);
  k_attn<<<dim3(64, 32), dim3(256), 0, stream>>>(q_ws, k_ws, vt_ws, x_bf);
  k_gemm<1><<<dim3(8, 64), dim3(256), 0, stream>>>(x_bf, wo_t, b_o, out,
                                                   nullptr, nullptr, nullptr, 8192, 1024, 1024);
}

// Round 3
// 188.285 us; speedup vs baseline: 1.3336x; 1.1157x over previous
//
#include <hip/hip_runtime.h>
#include <hip/hip_bf16.h>
#include <stdint.h>

// MHA: x[4,2048,1024] fp32 -> out fp32. All GEMMs in bf16 MFMA 16x16x32, fp32 accum.
// B=4, C=2048, D=1024, H=16, Dh=64.

typedef __attribute__((ext_vector_type(8))) short short8;   // 8 bf16 (4 VGPRs) MFMA A/B frag
typedef __attribute__((ext_vector_type(4))) short short4v;
typedef __attribute__((ext_vector_type(4))) float f32x4;    // MFMA C/D frag

#define AS1 __attribute__((address_space(1)))
#define AS3 __attribute__((address_space(3)))

static __device__ __forceinline__ short f2bf(float f) {
  union { float f; uint32_t u; } v; v.f = f;
  uint32_t r = v.u + 0x7fffu + ((v.u >> 16) & 1u);   // RNE
  return (short)(r >> 16);
}

static __device__ __forceinline__ short f2bfh(float f) {
  __hip_bfloat16 h = __float2bfloat16(f);             // HW cvt, pairs fuse to v_cvt_pk_bf16_f32
  return *reinterpret_cast<short*>(&h);
}

static __device__ __forceinline__ void gload_lds16(const void* g, void* l) {
  __builtin_amdgcn_global_load_lds((const AS1 void*)g, (AS3 void*)l, 16, 0, 0);
}

// ---------------- x fp32 -> bf16 ----------------
__global__ __launch_bounds__(256) void k_cvt_x(const float* __restrict__ x,
                                               short* __restrict__ xb) {
  long i = ((long)blockIdx.x * 256 + threadIdx.x) * 4;
  const float4 v = *(const float4*)(x + i);
  short4v o;
  o[0] = f2bf(v.x); o[1] = f2bf(v.y); o[2] = f2bf(v.z); o[3] = f2bf(v.w);
  *(short4v*)(xb + i) = o;
}

// ---------------- W [K][N] fp32 -> Wt [N][K] bf16 ----------------
__global__ __launch_bounds__(256) void k_transpose_bf(const float* __restrict__ W,
                                                      short* __restrict__ Wt,
                                                      int K, int N) {
  __shared__ float t[64][65];
  const int nb = blockIdx.x * 64, kb = blockIdx.y * 64;
  const int tid = threadIdx.x;
#pragma unroll
  for (int i = 0; i < 16; ++i) {
    int idx = i * 256 + tid; int r = idx >> 6, c = idx & 63;
    t[r][c] = W[(long)(kb + r) * N + nb + c];
  }
  __syncthreads();
#pragma unroll
  for (int i = 0; i < 16; ++i) {
    int idx = i * 256 + tid; int r = idx >> 6, c = idx & 63;
    Wt[(long)(nb + r) * K + kb + c] = f2bf(t[c][r]);
  }
}

// ---------------- bf16 GEMM, 128x128 tile, BK=32, DOUBLE-BUFFERED (T3 2-phase) ----
// A [M][K] bf16 row-major, Bt [N][K] bf16 row-major (= B^T). C = A*B + bias.
// K-loop: STAGE(buf^1, t+1) issued BEFORE ds_read+MFMA of buf; one barrier per
// K-step (__syncthreads' implicit vmcnt(0) drains the prefetch).
// EPI 0: scatter to Q (x0.125) / K / V^T bf16 workspaces (V^T via 8B short4 stores).
// EPI 1: fp32 C + bias.
template <int EPI>
__global__ __launch_bounds__(256)
void k_gemm(const short* __restrict__ A, const short* __restrict__ Bt,
            const float* __restrict__ bias, float* __restrict__ Cf,
            short* __restrict__ q_ws, short* __restrict__ k_ws, short* __restrict__ vt_ws,
            int M, int N, int K) {
  __shared__ __align__(16) short a_sh[2][128 * 32];
  __shared__ __align__(16) short b_sh[2][128 * 32];
  const int tid = threadIdx.x;
  const int lane = tid & 63, wid = tid >> 6;
  const int l15 = lane & 15, lg = lane >> 4;
  const int wr = wid >> 1, wc = wid & 1;                 // 2x2 waves, 64x64 each
  const int m0 = blockIdx.y * 128, n0 = blockIdx.x * 128;

  f32x4 acc[4][4] = {};

  const int r0 = tid >> 2, g0 = tid & 3;                 // staging: row r0(+64), 8-elem granule g0
  const short* ga0 = A + (long)(m0 + r0) * K + g0 * 8;
  const short* gb0 = Bt + (long)(n0 + r0) * K + g0 * 8;

#define GSTAGE(buf, ks)                                                             \
  {                                                                                 \
    _Pragma("unroll")                                                               \
    for (int i = 0; i < 2; ++i) {                                                   \
      gload_lds16(ga0 + (long)i * 64 * K + (ks), &a_sh[buf][(i * 256 + tid) * 8]);  \
      gload_lds16(gb0 + (long)i * 64 * K + (ks), &b_sh[buf][(i * 256 + tid) * 8]);  \
    }                                                                               \
  }

  GSTAGE(0, 0);
  __syncthreads();

  const int nt = K >> 5;
  int cur = 0;
  for (int t = 0; t < nt; ++t) {
    if (t + 1 < nt) GSTAGE(cur ^ 1, (t + 1) * 32);

    short8 af[4], bfr[4];
#pragma unroll
    for (int m = 0; m < 4; ++m)
      af[m] = *(const short8*)(&a_sh[cur][(wr * 64 + m * 16 + l15) * 32 + lg * 8]);
#pragma unroll
    for (int n = 0; n < 4; ++n)
      bfr[n] = *(const short8*)(&b_sh[cur][(wc * 64 + n * 16 + l15) * 32 + lg * 8]);
#pragma unroll
    for (int m = 0; m < 4; ++m)
#pragma unroll
      for (int n = 0; n < 4; ++n)
        acc[m][n] = __builtin_amdgcn_mfma_f32_16x16x32_bf16(af[m], bfr[n], acc[m][n], 0, 0, 0);

    __syncthreads();     // implicit vmcnt(0): next-tile prefetch landed; reads of cur done
    cur ^= 1;
  }
#undef GSTAGE

  // epilogue: C/D layout row=(lane>>4)*4+reg, col=lane&15 (m89-verified)
#pragma unroll
  for (int mm = 0; mm < 4; ++mm) {
#pragma unroll
    for (int nn = 0; nn < 4; ++nn) {
      const int n = n0 + wc * 64 + nn * 16 + l15;
      const int mb = m0 + wr * 64 + mm * 16 + lg * 4;
      if (EPI == 1) {
#pragma unroll
        for (int r = 0; r < 4; ++r)
          Cf[(long)(mb + r) * N + n] = acc[mm][nn][r] + bias[n];
      } else {
        const int which = n >> 10;            // uniform per n-tile (n0 multiple of 128)
        const int h = (n >> 6) & 15, d = n & 63;
        const int b = mb >> 11, c = mb & 2047;  // 4-run never crosses the 2048 boundary
        const int bh = b * 16 + h;
        const float bi = bias[n];
        if (which == 2) {                     // V^T: 4 c-consecutive regs -> one 8B store
          short4v o;
#pragma unroll
          for (int r = 0; r < 4; ++r) o[r] = f2bf(acc[mm][nn][r] + bi);
          *(short4v*)(vt_ws + ((long)bh * 64 + d) * 2048 + c) = o;
        } else if (which == 0) {
#pragma unroll
          for (int r = 0; r < 4; ++r)
            q_ws[((long)bh * 2048 + c + r) * 64 + d] = f2bf((acc[mm][nn][r] + bi) * 0.125f);
        } else {
#pragma unroll
          for (int r = 0; r < 4; ++r)
            k_ws[((long)bh * 2048 + c + r) * 64 + d] = f2bf(acc[mm][nn][r] + bi);
        }
      }
    }
  }
}

// ---------------- flash attention, swapped-operand (m214 structure) ----------------
// grid (B*H, C/64); block 256 = 4 waves x 16 q-rows each. KV tiles of 64, double-buffered.
// QK^T swapped: S^T = mfma(K_frag, Q_frag) -> lane holds 16 S values for ONE q (= lane&15).
// Softmax fully in-register (15 fmax + 2 shfl). PV swapped: O^T = mfma(V^T_frag, P_frag)
// with kv-permutation sigma(lg,i)=16*(i>>2)+4lg+(i&3) so the P B-frag is the lane's own
// 16 exp values (zero cross-lane, zero LDS for P). V A-frag = 2x ds_read_b64 per MFMA.
// LDS tiles row=128B -> XOR-swizzle 16B granules with (row&7); row&7 == l15&7 for all frag
// reads, so swizzled offsets are lane constants. gload_lds writes linearly; swizzle is
// applied on the GLOBAL source (m173).
__global__ __launch_bounds__(256)
void k_attn(const short* __restrict__ q_ws, const short* __restrict__ k_ws,
            const short* __restrict__ vt_ws, short* __restrict__ attn_out) {
  __shared__ __align__(16) short k_sh[2][64 * 64];
  __shared__ __align__(16) short v_sh[2][64 * 64];   // V^T tile: row=d, col=kv

  const int tid = threadIdx.x;
  const int lane = tid & 63, wid = tid >> 6;
  const int l15 = lane & 15, lg = lane >> 4;
  const int bh = blockIdx.x;
  const int qt = (int)gridDim.y - 1 - (int)blockIdx.y;   // heavy blocks first
  const int b = bh >> 4, h = bh & 15;
  const int qw = qt * 64 + wid * 16;                     // wave's q base
  const int q_glob = qw + l15;                           // this lane's q row

  // Q B-frags (lane: q=l15 col, d=lg*8.. contiguous), Q pre-scaled by 1/8
  const short* qrow = q_ws + ((long)bh * 2048 + q_glob) * 64;
  const short8 qf0 = *(const short8*)(qrow + lg * 8);
  const short8 qf1 = *(const short8*)(qrow + 32 + lg * 8);

  // lane-constant swizzled LDS byte offsets (swizzle key s7 = row&7 = l15&7)
  const int s7 = l15 & 7;
  const int koff0 = ((lg ^ s7) << 4);          // K granule lg   (d 8lg..8lg+7)
  const int koff1 = (((4 + lg) ^ s7) << 4);    // K granule 4+lg (d 32+8lg..)
  const int vsub = (lg & 1) * 8, vg = lg >> 1;
  int voff[4];
#pragma unroll
  for (int m2 = 0; m2 < 4; ++m2)               // V bytes {8lg,32+8lg,64+8lg,96+8lg}
    voff[m2] = (((2 * m2 + vg) ^ s7) << 4) | vsub;

  f32x4 accO[4] = {};                          // O^T: lane holds d=dt*16+lg*4+r, q=l15
  float mrow = -1e30f, lrow = 0.f;

  const int srow = tid >> 3, sg = tid & 7;     // staging granule (row, col)
  const int nkv = qt + 1;

#define STAGE(buf, kv)                                                              \
  {                                                                                 \
    _Pragma("unroll")                                                               \
    for (int i = 0; i < 2; ++i) {                                                   \
      int row = i * 32 + srow;                                                      \
      int gl = sg ^ (row & 7);                                                      \
      gload_lds16(k_ws + ((long)bh * 2048 + (kv) + row) * 64 + gl * 8,              \
                  &k_sh[buf][(i * 256 + tid) * 8]);                                 \
      gload_lds16(vt_ws + ((long)bh * 64 + row) * 2048 + (kv) + gl * 8,             \
                  &v_sh[buf][(i * 256 + tid) * 8]);                                 \
    }                                                                               \
  }

  STAGE(0, 0);
  asm volatile("s_waitcnt vmcnt(0)" ::: "memory");
  __syncthreads();

  int cur = 0;
  for (int t = 0; t < nkv; ++t) {
    const int kv0 = t * 64;
    if (t + 1 < nkv) STAGE(cur ^ 1, kv0 + 64);

    const char* ksh = (const char*)k_sh[cur];
    const char* vsh = (const char*)v_sh[cur];

    // S^T tiles: st[j][r] = S[q=l15][kv = kv0 + 16j + 4lg + r]
    f32x4 st[4];
#pragma unroll
    for (int j = 0; j < 4; ++j) {
      const char* kr = ksh + (j * 16 + l15) * 128;
      short8 kf0 = *(const short8*)(kr + koff0);
      short8 kf1 = *(const short8*)(kr + koff1);
      f32x4 z = {};
      z = __builtin_amdgcn_mfma_f32_16x16x32_bf16(kf0, qf0, z, 0, 0, 0);
      z = __builtin_amdgcn_mfma_f32_16x16x32_bf16(kf1, qf1, z, 0, 0, 0);
      st[j] = z;
    }

    // causal mask (diagonal tile only)
    if (kv0 + 64 > qw) {
#pragma unroll
      for (int j = 0; j < 4; ++j) {
        int kvr = kv0 + j * 16 + lg * 4;
#pragma unroll
        for (int r = 0; r < 4; ++r)
          if (kvr + r > q_glob) st[j][r] = -1e30f;
      }
    }

    // online softmax: all state per-lane (q = l15)
    float a0 = fmaxf(fmaxf(st[0][0], st[0][1]), fmaxf(st[0][2], st[0][3]));
    float a1 = fmaxf(fmaxf(st[1][0], st[1][1]), fmaxf(st[1][2], st[1][3]));
    float a2 = fmaxf(fmaxf(st[2][0], st[2][1]), fmaxf(st[2][2], st[2][3]));
    float a3 = fmaxf(fmaxf(st[3][0], st[3][1]), fmaxf(st[3][2], st[3][3]));
    float mx = fmaxf(fmaxf(a0, a1), fmaxf(a2, a3));
    mx = fmaxf(mx, __shfl_xor(mx, 16));
    mx = fmaxf(mx, __shfl_xor(mx, 32));
    const float mnew = fmaxf(mrow, mx);
    const float sc = __expf(mrow - mnew);
    mrow = mnew;
    lrow *= sc;
#pragma unroll
    for (int dt = 0; dt < 4; ++dt) {
      accO[dt][0] *= sc; accO[dt][1] *= sc; accO[dt][2] *= sc; accO[dt][3] *= sc;
    }
    float ps = 0.f;
#pragma unroll
    for (int j = 0; j < 4; ++j)
#pragma unroll
      for (int r = 0; r < 4; ++r) {
        float e = __expf(st[j][r] - mnew);
        st[j][r] = e;
        ps += e;
      }
    lrow += ps;   // partial over this lane's 16 kv slots; lg-reduced at end

    // pack P to bf16 B-frags (lane's own values; slot i of frag1 = sigma(lg,i))
    short8 pb0, pb1;
#pragma unroll
    for (int r = 0; r < 4; ++r) {
      pb0[r]     = f2bfh(st[0][r]);
      pb0[4 + r] = f2bfh(st[1][r]);
      pb1[r]     = f2bfh(st[2][r]);
      pb1[4 + r] = f2bfh(st[3][r]);
    }

    // O^T += V^T . P^T  (A-frag slot (lg,i) = V^T[d][sigma(lg,i)], 2x b64 per frag)
#pragma unroll
    for (int dt = 0; dt < 4; ++dt) {
      const char* vr = vsh + (dt * 16 + l15) * 128;
      union { short8 s8; short4v s4[2]; } vf1, vf2;
      vf1.s4[0] = *(const short4v*)(vr + voff[0]);
      vf1.s4[1] = *(const short4v*)(vr + voff[1]);
      accO[dt] = __builtin_amdgcn_mfma_f32_16x16x32_bf16(vf1.s8, pb0, accO[dt], 0, 0, 0);
      vf2.s4[0] = *(const short4v*)(vr + voff[2]);
      vf2.s4[1] = *(const short4v*)(vr + voff[3]);
      accO[dt] = __builtin_amdgcn_mfma_f32_16x16x32_bf16(vf2.s8, pb1, accO[dt], 0, 0, 0);
    }

    asm volatile("s_waitcnt vmcnt(0)" ::: "memory");
    __syncthreads();
    cur ^= 1;
  }
#undef STAGE

  // epilogue: O = O^T / l ; write [B,C,H*Dh] bf16, 8B stores
  float lt = lrow;
  lt += __shfl_xor(lt, 16);
  lt += __shfl_xor(lt, 32);
  const float inv = 1.0f / lt;
  short* obase = attn_out + ((long)b * 2048 + q_glob) * 1024 + h * 64;
#pragma unroll
  for (int dt = 0; dt < 4; ++dt) {
    short4v o;
#pragma unroll
    for (int r = 0; r < 4; ++r) o[r] = f2bfh(accO[dt][r] * inv);
    *(short4v*)(obase + dt * 16 + lg * 4) = o;
  }
}

// ---------------- launch ----------------
extern "C" void kernel_launch(void* const* d_in, const int* in_sizes, int n_in,
                              void* d_out, int out_size, void* d_ws, size_t ws_size,
                              hipStream_t stream) {
  const float* x     = (const float*)d_in[0];
  const float* W_qkv = (const float*)d_in[1];
  const float* b_qkv = (const float*)d_in[2];
  const float* W_o   = (const float*)d_in[3];
  const float* b_o   = (const float*)d_in[4];
  float* out = (float*)d_out;

  char* ws = (char*)d_ws;
  short* x_bf   = (short*)(ws);               // 16 MB; reused as attn_out after GEMM0
  short* wqkv_t = (short*)(ws + 16777216);    // 6 MB  [3072][1024]
  short* wo_t   = (short*)(ws + 23068672);    // 2 MB  [1024][1024]
  short* q_ws   = (short*)(ws + 25165824);    // 16 MB [B*H][C][64], pre-scaled
  short* k_ws   = (short*)(ws + 41943040);    // 16 MB [B*H][C][64]
  short* vt_ws  = (short*)(ws + 58720256);    // 16 MB [B*H][64][C]  (V^T)

  k_cvt_x<<<dim3(8192), dim3(256), 0, stream>>>(x, x_bf);
  k_transpose_bf<<<dim3(48, 16), dim3(256), 0, stream>>>(W_qkv, wqkv_t, 1024, 3072);
  k_transpose_bf<<<dim3(16, 16), dim3(256), 0, stream>>>(W_o, wo_t, 1024, 1024);
  k_gemm<0><<<dim3(24, 64), dim3(256), 0, stream>>>(x_bf, wqkv_t, b_qkv, nullptr,
                                                    q_ws, k_ws, vt_ws, 8192, 3072, 1024);
  k_attn<<<dim3(64, 32), dim3(256), 0, stream>>>(q_ws, k_ws, vt_ws, x_bf);
  k_gemm<1><<<dim3(8, 64), dim3(256), 0, stream>>>(x_bf, wo_t, b_o, out,
                                                   nullptr, nullptr, nullptr, 8192, 1024, 1024);
}